// Round 14
// baseline (430.427 us; speedup 1.0000x reference)
//
#include <hip/hip_runtime.h>

#define N_NODES 50000
#define N_EDGES 800000
#define C 128
#define N_GRAPHS 512
#define OUTDIM 5
#define BN_EPS 1e-5f
#define NB_SCAN 196      // ceil(50000/256)
#define N_STRIPES 3125   // 50000/16 exact
#define SCAT_SUB 100     // subgrids per XCD slice; grid = 8*SCAT_SUB

typedef short bs8 __attribute__((ext_vector_type(8)));   // 8 bf16 (4 VGPR) MFMA operand
typedef float f32x4 __attribute__((ext_vector_type(4))); // MFMA accumulator
typedef unsigned short us8 __attribute__((ext_vector_type(8)));

__device__ __forceinline__ unsigned short f2b(float f) {  // f32 -> bf16 RNE
    unsigned u = __float_as_uint(f);
    u += 0x7fffu + ((u >> 16) & 1u);
    return (unsigned short)(u >> 16);
}
__device__ __forceinline__ float b2f(unsigned v) {        // bf16 bits -> f32
    return __uint_as_float(v << 16);
}
__device__ __forceinline__ unsigned short f2h(float f) {  // f32 -> fp16 bits
    union { _Float16 h; unsigned short s; } cv;
    cv.h = (_Float16)f;
    return cv.s;
}
__device__ __forceinline__ float h2f(unsigned short s) {  // fp16 bits -> f32
    union { unsigned short s; _Float16 h; } cv;
    cv.s = s;
    return (float)cv.h;
}

// ================= f32 -> bf16 conversion (x0) =================
__global__ __launch_bounds__(256) void conv_kernel(const float* __restrict__ in,
                                                   unsigned short* __restrict__ out, int n4)
{
    int i = blockIdx.x * 256 + threadIdx.x;
    if (i < n4) {
        float4 v = reinterpret_cast<const float4*>(in)[i];
        ushort4 o;
        o.x = f2b(v.x); o.y = f2b(v.y); o.z = f2b(v.z); o.w = f2b(v.w);
        reinterpret_cast<ushort4*>(out)[i] = o;
    }
}

// all four 128x128 weight matrices in one launch
__global__ __launch_bounds__(256) void convw_kernel(const float* __restrict__ w0,
                                                    const float* __restrict__ w1,
                                                    const float* __restrict__ w2,
                                                    const float* __restrict__ w3,
                                                    unsigned short* __restrict__ out)
{
    const float* src[4] = {w0, w1, w2, w3};
    int m = blockIdx.x >> 4;
    int i = (blockIdx.x & 15) * 256 + threadIdx.x;
    float4 v = reinterpret_cast<const float4*>(src[m])[i];
    ushort4 o;
    o.x = f2b(v.x); o.y = f2b(v.y); o.z = f2b(v.z); o.w = f2b(v.w);
    reinterpret_cast<ushort4*>(out + m * 16384)[i] = o;
}

// ================= CSR build =================
__global__ __launch_bounds__(256) void hist_kernel(const int* __restrict__ ei,
                                                   int* __restrict__ deg)
{
    int e = blockIdx.x * 256 + threadIdx.x;
    atomicAdd(&deg[ei[N_EDGES + e]], 1);
}

__global__ __launch_bounds__(256) void scan1_kernel(const int* __restrict__ deg,
                                                    int* __restrict__ rowptr,
                                                    int* __restrict__ bsum)
{
    __shared__ int sh[256];
    int tid = threadIdx.x;
    int i = blockIdx.x * 256 + tid;
    int v = (i < N_NODES) ? deg[i] : 0;
    sh[tid] = v;
    __syncthreads();
    #pragma unroll
    for (int off = 1; off < 256; off <<= 1) {
        int t = (tid >= off) ? sh[tid - off] : 0;
        __syncthreads();
        sh[tid] += t;
        __syncthreads();
    }
    if (i < N_NODES) rowptr[i] = sh[tid] - v;
    if (tid == 255) bsum[blockIdx.x] = sh[255];
}

__global__ __launch_bounds__(256) void scan2_kernel(int* __restrict__ bsum)
{
    __shared__ int sh[256];
    int tid = threadIdx.x;
    int v = (tid < NB_SCAN) ? bsum[tid] : 0;
    sh[tid] = v;
    __syncthreads();
    #pragma unroll
    for (int off = 1; off < 256; off <<= 1) {
        int t = (tid >= off) ? sh[tid - off] : 0;
        __syncthreads();
        sh[tid] += t;
        __syncthreads();
    }
    if (tid < NB_SCAN) bsum[tid] = sh[tid] - v;
}

__global__ __launch_bounds__(256) void scan3_kernel(const int* __restrict__ bsum,
                                                    int* __restrict__ rowptr,
                                                    int* __restrict__ cursor)
{
    int i = blockIdx.x * 256 + threadIdx.x;
    if (i < N_NODES) {
        int v = rowptr[i] + bsum[blockIdx.x];
        rowptr[i] = v;
        cursor[i] = v;
    }
    if (i == 0) rowptr[N_NODES] = N_EDGES;
}

// XCD-partitioned scatter (R13: WRITE 54->under-43us; keep)
__global__ __launch_bounds__(256) void scatter_kernel(const int* __restrict__ ei,
                                                      const float* __restrict__ ew,
                                                      int* __restrict__ cursor,
                                                      unsigned* __restrict__ csr)
{
    const int r   = blockIdx.x & 7;
    const int sub = blockIdx.x >> 3;
    const int lo  = r * (N_NODES / 8);
    const int hi  = lo + (N_NODES / 8);
    for (int e = sub * 256 + threadIdx.x; e < N_EDGES; e += SCAT_SUB * 256) {
        int dst = ei[N_EDGES + e];
        if (dst >= lo && dst < hi) {
            int pos = atomicAdd(&cursor[dst], 1);
            csr[pos] = ((unsigned)ei[e] << 16) | (unsigned)f2h(ew[e]);
        }
    }
}

// ================= FUSED aggr + GEMM1 + BN-stats =================
// Per 16-row stripe: 4 waves aggregate h = x + sum relu(x[src]+w*We+be) into LDS
// (wave w -> nodes row0+4w..+3, lane -> 2 channels), barrier, then MFMA from LDS
// (A-frag = ds_read_b128 from padded [16][136] tile -> 2-way bank alias, free).
// Kills the h global round-trip (2x25.6MB) and the separate aggr launch.
// Output: t = bf16(h@W1.T + b1), plus column sum/sumsq for BN.
__global__ __launch_bounds__(256) void famg_kernel(
    const unsigned short* __restrict__ x,
    const unsigned* __restrict__ csr,
    const int* __restrict__ rowptr,
    const float* __restrict__ We,
    const float* __restrict__ be,
    const unsigned short* __restrict__ Wb,
    const float* __restrict__ bias,
    unsigned short* __restrict__ outb,
    float* __restrict__ gsum,
    float* __restrict__ gsq)
{
    __shared__ __align__(16) unsigned short hs[16][136];       // h tile, +8 pad
    __shared__ __align__(16) unsigned short xpose[4][16][40];  // epilogue transpose
    const int wave = threadIdx.x >> 6;
    const int lane = threadIdx.x & 63;
    const int colbase = wave << 5;
    const int lr = lane & 15;
    const int lk = (lane >> 4) << 3;

    // W frags + bias issued first: in flight during first aggr phase
    bs8 bf[2][4];
    #pragma unroll
    for (int ct = 0; ct < 2; ++ct)
        #pragma unroll
        for (int kc = 0; kc < 4; ++kc)
            bf[ct][kc] = *reinterpret_cast<const bs8*>(
                &Wb[(size_t)(colbase + ct * 16 + lr) * C + kc * 32 + lk]);
    const float bi0 = bias[colbase + lr];
    const float bi1 = bias[colbase + 16 + lr];

    const int c = lane * 2;
    const float2 wev = *reinterpret_cast<const float2*>(&We[c]);
    const float2 bev = *reinterpret_cast<const float2*>(&be[c]);

    float ssum0 = 0.f, ssq0 = 0.f, ssum1 = 0.f, ssq1 = 0.f;

    for (int s = blockIdx.x; s < N_STRIPES; s += gridDim.x) {
        const int row0 = s << 4;

        // ---- aggr phase: this wave's 4 nodes
        #pragma unroll
        for (int i = 0; i < 4; ++i) {
            int node = row0 + wave * 4 + i;
            int p = rowptr[node], p1 = rowptr[node + 1];
            unsigned sv = *reinterpret_cast<const unsigned*>(&x[(size_t)node * C + c]);
            float ax = b2f(sv & 0xffffu), ay = b2f(sv >> 16);
            for (; p + 4 <= p1; p += 4) {
                unsigned e0 = csr[p], e1 = csr[p + 1], e2 = csr[p + 2], e3 = csr[p + 3];
                float w0 = h2f((unsigned short)e0), w1 = h2f((unsigned short)e1);
                float w2 = h2f((unsigned short)e2), w3 = h2f((unsigned short)e3);
                unsigned g0 = *reinterpret_cast<const unsigned*>(&x[(size_t)(e0 >> 16) * C + c]);
                unsigned g1 = *reinterpret_cast<const unsigned*>(&x[(size_t)(e1 >> 16) * C + c]);
                unsigned g2 = *reinterpret_cast<const unsigned*>(&x[(size_t)(e2 >> 16) * C + c]);
                unsigned g3 = *reinterpret_cast<const unsigned*>(&x[(size_t)(e3 >> 16) * C + c]);
                float m;
                m = b2f(g0 & 0xffffu) + w0 * wev.x + bev.x; ax += fmaxf(m, 0.f);
                m = b2f(g0 >> 16)     + w0 * wev.y + bev.y; ay += fmaxf(m, 0.f);
                m = b2f(g1 & 0xffffu) + w1 * wev.x + bev.x; ax += fmaxf(m, 0.f);
                m = b2f(g1 >> 16)     + w1 * wev.y + bev.y; ay += fmaxf(m, 0.f);
                m = b2f(g2 & 0xffffu) + w2 * wev.x + bev.x; ax += fmaxf(m, 0.f);
                m = b2f(g2 >> 16)     + w2 * wev.y + bev.y; ay += fmaxf(m, 0.f);
                m = b2f(g3 & 0xffffu) + w3 * wev.x + bev.x; ax += fmaxf(m, 0.f);
                m = b2f(g3 >> 16)     + w3 * wev.y + bev.y; ay += fmaxf(m, 0.f);
            }
            for (; p < p1; ++p) {
                unsigned e0 = csr[p];
                float w0 = h2f((unsigned short)e0);
                unsigned g0 = *reinterpret_cast<const unsigned*>(&x[(size_t)(e0 >> 16) * C + c]);
                float m;
                m = b2f(g0 & 0xffffu) + w0 * wev.x + bev.x; ax += fmaxf(m, 0.f);
                m = b2f(g0 >> 16)     + w0 * wev.y + bev.y; ay += fmaxf(m, 0.f);
            }
            unsigned o = (unsigned)f2b(ax) | ((unsigned)f2b(ay) << 16);
            *reinterpret_cast<unsigned*>(&hs[wave * 4 + i][c]) = o;
        }
        __syncthreads();   // hs ready

        bs8 af[4];
        #pragma unroll
        for (int kc = 0; kc < 4; ++kc)
            af[kc] = *reinterpret_cast<const bs8*>(&hs[lr][kc * 32 + lk]);
        __syncthreads();   // all waves done reading hs; next iter may overwrite

        f32x4 a0 = {0.f, 0.f, 0.f, 0.f};
        f32x4 a1 = {0.f, 0.f, 0.f, 0.f};
        #pragma unroll
        for (int kc = 0; kc < 4; ++kc) {
            a0 = __builtin_amdgcn_mfma_f32_16x16x32_bf16(af[kc], bf[0][kc], a0, 0, 0, 0);
            a1 = __builtin_amdgcn_mfma_f32_16x16x32_bf16(af[kc], bf[1][kc], a1, 0, 0, 0);
        }

        #pragma unroll
        for (int r = 0; r < 4; ++r) {
            int rl = ((lane >> 4) << 2) + r;
            float o0 = a0[r] + bi0;
            float o1 = a1[r] + bi1;
            ssum0 += o0; ssq0 += o0 * o0;
            ssum1 += o1; ssq1 += o1 * o1;
            xpose[wave][rl][lr]      = f2b(o0);
            xpose[wave][rl][lr + 16] = f2b(o1);
        }
        __builtin_amdgcn_sched_barrier(0);
        us8 v = *reinterpret_cast<const us8*>(&xpose[wave][lane >> 2][(lane & 3) * 8]);
        *reinterpret_cast<us8*>(
            &outb[(size_t)(row0 + (lane >> 2)) * C + colbase + (lane & 3) * 8]) = v;
        __builtin_amdgcn_sched_barrier(0);
    }

    ssum0 += __shfl_xor(ssum0, 16); ssum0 += __shfl_xor(ssum0, 32);
    ssq0  += __shfl_xor(ssq0, 16);  ssq0  += __shfl_xor(ssq0, 32);
    ssum1 += __shfl_xor(ssum1, 16); ssum1 += __shfl_xor(ssum1, 32);
    ssq1  += __shfl_xor(ssq1, 16);  ssq1  += __shfl_xor(ssq1, 32);
    if (lane < 16) {
        unsafeAtomicAdd(&gsum[colbase + lr], ssum0);
        unsafeAtomicAdd(&gsq[colbase + lr], ssq0);
        unsafeAtomicAdd(&gsum[colbase + 16 + lr], ssum1);
        unsafeAtomicAdd(&gsq[colbase + 16 + lr], ssq1);
    }
}

// ================= GEMM2 with fused BN (scale/shift from gsum/gsq in prologue) =================
// MODE 1: a = relu(bf16(A)*scale+shift); out = bf16(relu(a@W.T + bias))
// MODE 2: like MODE 1 but atomicMax-pool f32 into pooled[batch[row]*C+col]
template<int MODE>
__global__ __launch_bounds__(256) void mgemm_kernel(
    const unsigned short* __restrict__ A,
    const unsigned short* __restrict__ Wb,
    const float* __restrict__ bias,
    const float* __restrict__ gsum,
    const float* __restrict__ gsq,
    const float* __restrict__ g,
    const float* __restrict__ bt,
    const int* __restrict__ batch,
    unsigned short* __restrict__ outb,
    float* __restrict__ pooled)
{
    __shared__ __align__(16) unsigned short xpose[4][16][40];
    const int wave = threadIdx.x >> 6;
    const int lane = threadIdx.x & 63;
    const int colbase = wave << 5;
    const int lr = lane & 15;
    const int lk = (lane >> 4) << 3;

    bs8 bf[2][4];
    #pragma unroll
    for (int ct = 0; ct < 2; ++ct)
        #pragma unroll
        for (int kc = 0; kc < 4; ++kc)
            bf[ct][kc] = *reinterpret_cast<const bs8*>(
                &Wb[(size_t)(colbase + ct * 16 + lr) * C + kc * 32 + lk]);

    const float bi0 = bias[colbase + lr];
    const float bi1 = bias[colbase + 16 + lr];

    // fused bnfin: per-thread scale/shift for its 32 k-columns
    float sc[4][8], sh[4][8];
    #pragma unroll
    for (int kc = 0; kc < 4; ++kc)
        #pragma unroll
        for (int i = 0; i < 8; ++i) {
            int cc = kc * 32 + lk + i;
            float mu  = gsum[cc] * (1.f / N_NODES);
            float var = gsq[cc] * (1.f / N_NODES) - mu * mu;
            float scv = rsqrtf(var + BN_EPS) * g[cc];
            sc[kc][i] = scv;
            sh[kc][i] = bt[cc] - mu * scv;
        }

    int s = blockIdx.x;
    bs8 raw[4];
    #pragma unroll
    for (int kc = 0; kc < 4; ++kc)
        raw[kc] = *reinterpret_cast<const bs8*>(
            &A[(size_t)(s * 16 + lr) * C + kc * 32 + lk]);

    while (true) {
        const int snext = s + gridDim.x;
        bs8 rawn[4];
        if (snext < N_STRIPES) {
            #pragma unroll
            for (int kc = 0; kc < 4; ++kc)
                rawn[kc] = *reinterpret_cast<const bs8*>(
                    &A[(size_t)(snext * 16 + lr) * C + kc * 32 + lk]);
        }

        bs8 af[4];
        #pragma unroll
        for (int kc = 0; kc < 4; ++kc) {
            union { bs8 v; unsigned short u[8]; } pk;
            #pragma unroll
            for (int i = 0; i < 8; ++i) {
                float f = b2f((unsigned)(unsigned short)raw[kc][i]);
                pk.u[i] = f2b(fmaxf(f * sc[kc][i] + sh[kc][i], 0.f));
            }
            af[kc] = pk.v;
        }

        f32x4 a0 = {0.f, 0.f, 0.f, 0.f};
        f32x4 a1 = {0.f, 0.f, 0.f, 0.f};
        #pragma unroll
        for (int kc = 0; kc < 4; ++kc) {
            a0 = __builtin_amdgcn_mfma_f32_16x16x32_bf16(af[kc], bf[0][kc], a0, 0, 0, 0);
            a1 = __builtin_amdgcn_mfma_f32_16x16x32_bf16(af[kc], bf[1][kc], a1, 0, 0, 0);
        }

        const int row0 = s << 4;
        if (MODE == 2) {
            const int orow = row0 + ((lane >> 4) << 2);
            float o0[4], o1[4];
            #pragma unroll
            for (int r = 0; r < 4; ++r) {
                o0[r] = fmaxf(a0[r] + bi0, 0.f);
                o1[r] = fmaxf(a1[r] + bi1, 0.f);
            }
            int gA = batch[orow], gB = batch[orow + 3];
            if (gA == gB) {
                float m0 = fmaxf(fmaxf(o0[0], o0[1]), fmaxf(o0[2], o0[3]));
                float m1 = fmaxf(fmaxf(o1[0], o1[1]), fmaxf(o1[2], o1[3]));
                atomicMax(reinterpret_cast<int*>(&pooled[(size_t)gA * C + colbase + lr]),
                          __float_as_int(m0));
                atomicMax(reinterpret_cast<int*>(&pooled[(size_t)gA * C + colbase + 16 + lr]),
                          __float_as_int(m1));
            } else {
                #pragma unroll
                for (int r = 0; r < 4; ++r) {
                    int gg = batch[orow + r];
                    atomicMax(reinterpret_cast<int*>(&pooled[(size_t)gg * C + colbase + lr]),
                              __float_as_int(o0[r]));
                    atomicMax(reinterpret_cast<int*>(&pooled[(size_t)gg * C + colbase + 16 + lr]),
                              __float_as_int(o1[r]));
                }
            }
        } else {
            #pragma unroll
            for (int r = 0; r < 4; ++r) {
                int rl = ((lane >> 4) << 2) + r;
                float o0 = fmaxf(a0[r] + bi0, 0.f);
                float o1 = fmaxf(a1[r] + bi1, 0.f);
                xpose[wave][rl][lr]      = f2b(o0);
                xpose[wave][rl][lr + 16] = f2b(o1);
            }
            __builtin_amdgcn_sched_barrier(0);
            us8 v = *reinterpret_cast<const us8*>(&xpose[wave][lane >> 2][(lane & 3) * 8]);
            *reinterpret_cast<us8*>(
                &outb[(size_t)(row0 + (lane >> 2)) * C + colbase + (lane & 3) * 8]) = v;
            __builtin_amdgcn_sched_barrier(0);
        }

        if (snext >= N_STRIPES) break;
        #pragma unroll
        for (int kc = 0; kc < 4; ++kc) raw[kc] = rawn[kc];
        s = snext;
    }
}

// ================= final linear (f32 pooled) =================
__global__ __launch_bounds__(64) void final_kernel(const float* __restrict__ pooled,
                                                   const float* __restrict__ lw,
                                                   const float* __restrict__ lb,
                                                   float* __restrict__ out)
{
    int gph = blockIdx.x;
    int lane = threadIdx.x;
    float v0 = pooled[(size_t)gph * C + lane];
    float v1 = pooled[(size_t)gph * C + lane + 64];
    for (int o = 0; o < OUTDIM; ++o) {
        float p = v0 * lw[o * C + lane] + v1 * lw[o * C + lane + 64];
        #pragma unroll
        for (int off = 32; off > 0; off >>= 1) p += __shfl_down(p, off);
        if (lane == 0) out[gph * OUTDIM + o] = p + lb[o];
    }
}

extern "C" void kernel_launch(void* const* d_in, const int* in_sizes, int n_in,
                              void* d_out, int out_size, void* d_ws, size_t ws_size,
                              hipStream_t stream)
{
    const float* x0   = (const float*)d_in[0];
    const int*   ei   = (const int*)  d_in[1];
    const float* ew   = (const float*)d_in[2];
    const int*   batch= (const int*)  d_in[3];
    const float* We0  = (const float*)d_in[4];
    const float* be0  = (const float*)d_in[5];
    const float* W1_0 = (const float*)d_in[6];
    const float* b1_0 = (const float*)d_in[7];
    const float* g0   = (const float*)d_in[8];
    const float* bt0  = (const float*)d_in[9];
    const float* W2_0 = (const float*)d_in[10];
    const float* b2_0 = (const float*)d_in[11];
    const float* We1  = (const float*)d_in[12];
    const float* be1  = (const float*)d_in[13];
    const float* W1_1 = (const float*)d_in[14];
    const float* b1_1 = (const float*)d_in[15];
    const float* g1   = (const float*)d_in[16];
    const float* bt1  = (const float*)d_in[17];
    const float* W2_1 = (const float*)d_in[18];
    const float* b2_1 = (const float*)d_in[19];
    const float* lin_w= (const float*)d_in[20];
    const float* lin_b= (const float*)d_in[21];

    char* base = (char*)d_ws;
    unsigned short* xb = (unsigned short*)(base);              // 12.8 MB  bf16 x0
    unsigned short* tB = (unsigned short*)(base + 25600000);   // 12.8 MB  t
    unsigned short* xC = (unsigned short*)(base + 38400000);   // 12.8 MB  x1
    unsigned short* Wb = (unsigned short*)(base + 51200000);   // 4 x 32 KB bf16 W
    unsigned* csr  = (unsigned*)(base + 51400000);             // 3.2 MB (4B/edge)
    int*    deg    = (int*)(base + 57800000);                  // 200 KB
    int*    rowptr = (int*)(base + 58000000);                  // 200 KB
    int*    cursor = (int*)(base + 58200008);                  // 200 KB
    int*    bsum   = (int*)(base + 58400008);                  // ~1 KB
    float*  gsum   = (float*)(base + 58401024);
    float*  gsq    = gsum + 128;
    float*  pooled = (float*)(base + 58403072);                // 256 KB

    // ---- convert x0 + weights to bf16
    conv_kernel<<<6250, 256, 0, stream>>>(x0, xb, N_NODES * C / 4);
    convw_kernel<<<64, 256, 0, stream>>>(W1_0, W2_0, W1_1, W2_1, Wb);

    // ---- build CSR once
    hipMemsetAsync(deg, 0, N_NODES * sizeof(int), stream);
    hist_kernel<<<N_EDGES / 256, 256, 0, stream>>>(ei, deg);
    scan1_kernel<<<NB_SCAN, 256, 0, stream>>>(deg, rowptr, bsum);
    scan2_kernel<<<1, 256, 0, stream>>>(bsum);
    scan3_kernel<<<NB_SCAN, 256, 0, stream>>>(bsum, rowptr, cursor);
    scatter_kernel<<<SCAT_SUB * 8, 256, 0, stream>>>(ei, ew, cursor, csr);

    // ---- layer 1: fused aggr+GEMM1+stats, then BN-fused GEMM2
    hipMemsetAsync(gsum, 0, 256 * sizeof(float), stream);
    famg_kernel<<<768, 256, 0, stream>>>(xb, csr, rowptr, We0, be0,
                                         Wb + 0 * 16384, b1_0, tB, gsum, gsq);
    mgemm_kernel<1><<<768, 256, 0, stream>>>(tB, Wb + 1 * 16384, b2_0,
                                             gsum, gsq, g0, bt0, nullptr, xC, nullptr);

    // ---- layer 2
    hipMemsetAsync(gsum, 0, 256 * sizeof(float), stream);
    famg_kernel<<<768, 256, 0, stream>>>(xC, csr, rowptr, We1, be1,
                                         Wb + 2 * 16384, b1_1, tB, gsum, gsq);
    hipMemsetAsync(pooled, 0, (size_t)N_GRAPHS * C * sizeof(float), stream);
    mgemm_kernel<2><<<768, 256, 0, stream>>>(tB, Wb + 3 * 16384, b2_1,
                                             gsum, gsq, g1, bt1, batch, nullptr, pooled);

    // ---- final linear
    final_kernel<<<N_GRAPHS, 64, 0, stream>>>(pooled, lin_w, lin_b, (float*)d_out);
}